// Round 1
// baseline (101.780 us; speedup 1.0000x reference)
//
#include <hip/hip_runtime.h>
#include <stdint.h>

#define M52 0xFFFFFFFFFFFFFULL

__device__ __forceinline__ uint64_t shfl64(uint64_t x, int src) {
    int lo = __shfl((int)(uint32_t)x, src, 64);
    int hi = __shfl((int)(uint32_t)(x >> 32), src, 64);
    return ((uint64_t)(uint32_t)hi << 32) | (uint64_t)(uint32_t)lo;
}

// One thread per row. Wave (64 lanes) cooperates on 64 consecutive rows for
// coalesced load (ballot-pack) and store (shfl-unpack).
__global__ __launch_bounds__(256) void fp64div_kernel(
    const float* __restrict__ A, const float* __restrict__ B,
    float* __restrict__ out, int n_rows)
{
    const int tid  = blockIdx.x * blockDim.x + threadIdx.x;
    const int lane = threadIdx.x & 63;
    const int wave_base = tid & ~63;           // first row of this wave
    if (wave_base >= n_rows) return;           // n_rows % 64 == 0

    const float* Ap = A + (size_t)wave_base * 64 + lane;
    const float* Bp = B + (size_t)wave_base * 64 + lane;

    // ---- pack: row r of this wave's chunk -> 64-bit word owned by lane r ----
    // ballot bit l == lane l's predicate == bit-position l of row r.
    uint64_t my_a = 0, my_b = 0;
    #pragma unroll
    for (int rb = 0; rb < 64; rb += 16) {
        float va[16], vb[16];
        #pragma unroll
        for (int i = 0; i < 16; ++i) va[i] = Ap[(size_t)(rb + i) * 64];
        #pragma unroll
        for (int i = 0; i < 16; ++i) vb[i] = Bp[(size_t)(rb + i) * 64];
        #pragma unroll
        for (int i = 0; i < 16; ++i) {
            uint64_t ma = __ballot(va[i] != 0.0f);
            if (lane == rb + i) my_a = ma;
            uint64_t mb = __ballot(vb[i] != 0.0f);
            if (lane == rb + i) my_b = mb;
        }
    }

    // Bit-reversed row == IEEE-754 binary64 bit pattern.
    const uint64_t av = __brevll(my_a);
    const uint64_t bv = __brevll(my_b);

    const uint32_t sa = (uint32_t)(av >> 63), sb = (uint32_t)(bv >> 63);
    const uint32_t s_out = sa ^ sb;
    const uint32_t Ea = (uint32_t)(av >> 52) & 0x7FFu;
    const uint32_t Eb = (uint32_t)(bv >> 52) & 0x7FFu;
    const uint64_t Ma = av & M52;
    const uint64_t Mb = bv & M52;

    const bool ea_all1 = (Ea == 0x7FFu), eb_all1 = (Eb == 0x7FFu);
    const bool ea_zero = (Ea == 0u),     eb_zero = (Eb == 0u);
    const bool ma_zero = (Ma == 0ull),   mb_zero = (Mb == 0ull);
    const bool a_zero = ea_zero && ma_zero, b_zero = eb_zero && mb_zero;
    const bool a_inf  = ea_all1 && ma_zero, b_inf  = eb_all1 && mb_zero;
    const bool a_nan  = ea_all1 && !ma_zero, b_nan = eb_all1 && !mb_zero;

    const bool r_nan  = a_nan || b_nan || (a_zero && b_zero) || (a_inf && b_inf);
    const bool r_inf  = (!a_zero && b_zero) || (a_inf && !b_inf);
    const bool r_zero = (a_zero && !b_zero) || (!a_inf && b_inf);

    // 13-bit circuit exponent arithmetic (mod 8192)
    const uint32_t exp13 = (Ea - Eb + 1023u) & 0x1FFFu;

    // 57-step restoring division on 55-bit values (invariant R < 2D keeps
    // everything < 2^55, so the circuit's 55-bit truncation is a no-op).
    uint64_t R = (1ULL << 53) | (Ma << 1);
    const uint64_t D = (1ULL << 53) | (Mb << 1);
    uint64_t Q = 0;
    #pragma unroll
    for (int i = 0; i < 56; ++i) {
        const bool ge = (R >= D);
        const uint64_t t = R - D;
        R = ge ? t : R;
        Q = (Q << 1) | (ge ? 1u : 0u);
        R <<= 1;
    }
    {   // final step, no shift
        const bool ge = (R >= D);
        const uint64_t t = R - D;
        R = ge ? t : R;
        Q = (Q << 1) | (ge ? 1u : 0u);
    }
    // Q bit (56-i) == Q_raw[i]; R == final remainder.

    const uint32_t q0 = (uint32_t)(Q >> 56) & 1u;
    const uint32_t rem_nz = (R != 0ull) ? 1u : 0u;

    const uint64_t mant52 = q0 ? ((Q >> 4) & M52) : ((Q >> 3) & M52);
    const uint32_t rbit   = q0 ? ((uint32_t)(Q >> 3) & 1u) : ((uint32_t)(Q >> 2) & 1u);
    const uint32_t sticky = (q0 ? (((Q & 7ull) != 0ull) ? 1u : 0u)
                                : (((Q & 3ull) != 0ull) ? 1u : 0u)) | rem_nz;
    const uint32_t exp_f  = q0 ? exp13 : ((exp13 - 1u) & 0x1FFFu);

    const uint32_t lsb = (uint32_t)mant52 & 1u;
    const uint32_t rup = rbit & (sticky | lsb);
    // circuit quirk: 53-bit adder carry-out is identically 0, so mantissa
    // overflow wraps to 0 WITHOUT exponent bump.
    const uint64_t mant_final = (mant52 + rup) & M52;

    const uint32_t exp11    = exp_f & 0x7FFu;
    const bool overflow  = (exp_f >> 11) != 0u;            // bits 11|12
    const bool underflow = (((exp_f >> 12) & 1u) != 0u) || (exp_f == 0u);

    uint64_t res = ((uint64_t)s_out << 63) | ((uint64_t)exp11 << 52) | mant_final;
    const uint64_t zero_v = ((uint64_t)s_out << 63);
    const uint64_t inf_v  = zero_v | (0x7FFULL << 52);
    const uint64_t nan_v  = inf_v | (1ULL << 51);

    if (r_nan)        res = nan_v;
    else if (r_inf)   res = inf_v;
    else if (r_zero)  res = zero_v;
    else if (overflow) res = inf_v;
    else if (underflow) res = zero_v;

    const uint64_t out_word = __brevll(res);   // back to position-indexed bits

    // ---- store: unpack via shfl, coalesced 4B/lane ----
    float* Op = out + (size_t)wave_base * 64 + lane;
    #pragma unroll 8
    for (int r = 0; r < 64; ++r) {
        const uint64_t w = shfl64(out_word, r);
        Op[(size_t)r * 64] = (float)((uint32_t)(w >> lane) & 1u);
    }
}

extern "C" void kernel_launch(void* const* d_in, const int* in_sizes, int n_in,
                              void* d_out, int out_size, void* d_ws, size_t ws_size,
                              hipStream_t stream) {
    const float* A = (const float*)d_in[0];
    const float* B = (const float*)d_in[1];
    float* out = (float*)d_out;
    const int n_rows = in_sizes[0] / 64;
    const int threads = 256;
    const int blocks = (n_rows + threads - 1) / threads;
    fp64div_kernel<<<blocks, threads, 0, stream>>>(A, B, out, n_rows);
}